// Round 5
// baseline (538.962 us; speedup 1.0000x reference)
//
#include <hip/hip_runtime.h>
#include <hip/hip_fp16.h>

// Tree NN: reps = emb[tokens] (4096 x 128 x 128); 7x: reps = tanh(concat(pairs) @ W_tree^T + b);
// out = root @ W_cls^T + b_cls.
//
// R18 = R16's LDS-pipe attack with DEFENSIVE BARRIERS. R16/R17 both died with "container
// failed twice" (no pytest/absmax verdict — looks like infra), but after two strikes the
// only unaudited construct is removed: raw asm s_barrier between divergently-guarded
// regions -> plain __syncthreads(). The payload under test is unchanged:
//
// LDS-pipe theory: R15 proved occupancy is NOT the limiter (2x waves -> 1.35x SLOWER via
// 2x LDS read traffic). R13 issues 640 ds_read_b128/pair (every A-row read by all 4
// n-split waves = 4x duplication); at ~10-12cy each x3 blocks/CU = ~23k cy per 25.5k-cy
// pair-slot -> LDS data pipe ~90% saturated. That is the hidden wall (MfmaUtil 20 +
// VALUBusy 33 never summed to it; the LDS pipe has no headline counter).
//
//  1. 2x2 WAVE TILING (m x n): wave (wm=wid>>1, wn=wid&1); wn owns 4 n-tiles = 64 cols
//     (Wf[4][8] = 128 VGPR), wm owns half the m-tiles at L0/L1. Each A-row now read by
//     2 waves not 4 -> 320 ds_read_b128/pair (HALF of R13). MFMA count unchanged.
//  2. Tail levels (L2..L6, single m-tile) on wm0 waves only; wm1 idles to the barrier —
//     idle waves cost nothing on the saturated LDS pipe, duplicated reads would.
//  3. Register discipline for lb(256,3)'s 170-VGPR cap (R15's spill lesson): sequential
//     m in L0 (unroll 1 -> acc[4]=16 regs), single 8-deep MFMA chain per n-tile (4-way
//     ILP across n-tiles), classifier wc reloaded per pair inside L6.
//     Permanent ~142 (Wf 128 + bias 4 + toks + idx), peak ~168.
// Kept: bias folded into acc init, pair-contig LDS layout, conflict-free gather writes,
// fp16 MFMA 16x16x32, fp32 accumulate/tanh, lb(256,3), grid 768, batched L5/L6 tail.
// Dropped vs R16: raw lgkmcnt-only barriers (token-preload-in-flight was worth ~0 in
// R14's isolation; not worth a hang risk).

typedef _Float16 half8 __attribute__((ext_vector_type(8)));
typedef float floatx4 __attribute__((ext_vector_type(4)));

#define STRIDE 264   // 256 + 8 fp16 pad: A-row ds_read_b128 conflict-free
#define UROW   33    // uint4 per row
#define NPAIR  2048

__device__ __forceinline__ float fast_tanh(float x) {
  // No clamp needed: e=inf -> 1; e=0 -> -1. Inputs never NaN.
  float e = __expf(2.f * x);
  return 1.f - 2.f * __builtin_amdgcn_rcpf(e + 1.f);
}

__device__ __forceinline__ unsigned pkrtz(float a, float b) {
  auto h = __builtin_amdgcn_cvt_pkrtz(a, b);   // __fp16 ext_vector(2)
  return __builtin_bit_cast(unsigned, h);
}

// Gather: thread (row=t&63, seg=t>>6) covers leaf 2*row+(seg>>1), feature-half seg&1.
// Writes 8 uint4 at row*33 + seg*8 + j: 8 consecutive lanes hit 8 consecutive rows ->
// distinct bank-quads -> conflict-free phases. Pair-contiguous layout.
__device__ __forceinline__ void gather_leafhalf(int tok, const float* __restrict__ emb,
                                                _Float16* buf, int row, int seg) {
  const float4* src = (const float4*)emb + (size_t)tok * 32 + (seg & 1) * 16;
  uint4* dst = (uint4*)buf + row * UROW + seg * 8;
#pragma unroll
  for (int j = 0; j < 8; ++j) {
    float4 x = src[2 * j], y = src[2 * j + 1];
    uint4 w;
    w.x = pkrtz(x.x, x.y); w.y = pkrtz(x.z, x.w);
    w.z = pkrtz(y.x, y.y); w.w = pkrtz(y.z, y.w);
    dst[j] = w;
  }
}

// K=256 MFMA for one 16-row m-tile, FOUR n-tiles: 4 independent 8-deep chains (ILP
// across n). One ds_read_b128 feeds 4 MFMAs. Bias in chain init.
// A-frag: A[m=lane&15][k=quad*8+j]; B-frag: B[k=quad*8+j][n=lane&15];
// D: col=lane&15, row=quad*4+reg (verified layouts, learn_hip m89/m91).
__device__ __forceinline__ void mfma_k256_n4(const _Float16* arow, const half8 (&Wf)[4][8],
                                             const float (&bias)[4], floatx4 (&acc)[4]) {
#pragma unroll
  for (int i = 0; i < 4; ++i) acc[i] = (floatx4){bias[i], bias[i], bias[i], bias[i]};
#pragma unroll
  for (int ks = 0; ks < 8; ++ks) {
    half8 x = *(const half8*)(arow + ks * 32);
#pragma unroll
    for (int i = 0; i < 4; ++i)
      acc[i] = __builtin_amdgcn_mfma_f32_16x16x32_f16(x, Wf[i][ks], acc[i], 0, 0, 0);
  }
}

// One wave: 4 n-tiles (cols [col0, col0+64)) for MT_LOC m-tiles starting at mbase.
// Sequential m (unroll 1) caps live acc at 16 VGPR. Pair-contiguous store, MOUT mask.
// Stale rows above MOUT always hold finite tanh/leaf values; masked at store.
template<int MT_LOC, int MOUT>
__device__ __forceinline__ void level4(const _Float16* inb, _Float16* outb,
                                       const half8 (&Wf)[4][8], const float (&bias)[4],
                                       int mbase, int col0, int l15, int quad)
{
#pragma unroll 1
  for (int m = 0; m < MT_LOC; ++m) {
    floatx4 acc[4];
    mfma_k256_n4(inb + ((mbase + m) * 16 + l15) * STRIDE + quad * 8, Wf, bias, acc);
    const int mrow = (mbase + m) * 16 + quad * 4;
#pragma unroll
    for (int i = 0; i < 4; ++i) {
      const int col = col0 + i * 16 + l15;
#pragma unroll
      for (int r = 0; r < 4; ++r) {
        const int node = mrow + r;
        if (MOUT == 64 || node < MOUT) {   // compile-time short-circuit for L0
          float v = fast_tanh(acc[i][r]);
          outb[(node >> 1) * STRIDE + (node & 1) * 128 + col] = (_Float16)v;
        }
      }
    }
  }
}

__global__ __launch_bounds__(256, 3)   // 3 blocks/CU (LDS 53KB); VGPR cap 170
void tree_kernel(const int* __restrict__ tokens,
                 const float* __restrict__ embedding,
                 const float* __restrict__ W_tree,
                 const float* __restrict__ b_tree,
                 const float* __restrict__ W_cls,
                 const float* __restrict__ b_cls,
                 float* __restrict__ out)
{
  __shared__ __align__(16) _Float16 bufA[64 * STRIDE];   // leaves / even outputs (33.8 KB)
  __shared__ __align__(16) _Float16 bufB[32 * STRIDE];   // odd outputs (16.9 KB)
  __shared__ __align__(16) _Float16 bufC[4 * STRIDE];    // pair stash: L4 outs (2.1 KB)
  __shared__ float wavepart[2][2][3];                    // classifier partials (48 B)

  const int tid  = threadIdx.x;
  const int wid  = tid >> 6;
  const int lane = tid & 63;
  const int l15  = lane & 15;
  const int quad = lane >> 4;
  const int wn   = wid & 1;                // n-half: cols [64*wn, 64*wn+64)
  const int wm   = wid >> 1;               // m-half for L0/L1; wm0 runs the tail
  const int col0 = wn * 64;
  const int row  = tid & 63;               // gather destination row
  const int seg  = tid >> 6;               // gather leaf-half / feature-half segment
  const int tidx = 2 * row + (seg >> 1);   // this thread's token index within a sample

  // ---- stage this wave's 4 n-tiles of W_tree as B-fragments (128 VGPR) ----
  // B[k][n] = W_tree[e=n][h=k]  (einsum 'bnh,eh->bne' => out = comb @ W^T)
  half8 Wf[4][8];
#pragma unroll
  for (int i = 0; i < 4; ++i) {
    const int e = col0 + i * 16 + l15;
#pragma unroll
    for (int ks = 0; ks < 8; ++ks) {
      const int k = ks * 32 + quad * 8;
      const float4* p = (const float4*)(W_tree + e * 256 + k);
      float4 lo = p[0], hi = p[1];
      half8 f;
      f[0] = (_Float16)lo.x; f[1] = (_Float16)lo.y; f[2] = (_Float16)lo.z; f[3] = (_Float16)lo.w;
      f[4] = (_Float16)hi.x; f[5] = (_Float16)hi.y; f[6] = (_Float16)hi.z; f[7] = (_Float16)hi.w;
      Wf[i][ks] = f;
    }
  }
  float bias[4];
#pragma unroll
  for (int i = 0; i < 4; ++i) bias[i] = b_tree[col0 + i * 16 + l15];

  int tokA = tokens[(2 * blockIdx.x) * 128 + tidx];       // preloaded pair tokens
  int tokB = tokens[(2 * blockIdx.x + 1) * 128 + tidx];

#pragma unroll 1
  for (int p = blockIdx.x; p < NPAIR; p += gridDim.x) {
    int pn = p + gridDim.x;
    if (pn >= NPAIR) pn = p;               // last iteration: harmless self-reload

    // ---- s0 gather (token preloaded) + preload next-pair tokens ----
    gather_leafhalf(tokA, embedding, bufA, row, seg);
    const int tokAn = tokens[(2 * pn) * 128 + tidx];
    const int tokBn = tokens[(2 * pn + 1) * 128 + tidx];
    __syncthreads();

    // ---- s0 levels: L0..L4, stash L4-out in bufC rows 0-1 ----
    level4<2, 64>(bufA, bufB, Wf, bias, wm * 2, col0, l15, quad);   // L0: wm-split
    __syncthreads();
    level4<1, 32>(bufB, bufA, Wf, bias, wm,     col0, l15, quad);   // L1: wm-split
    __syncthreads();
    if (wm == 0) level4<1, 16>(bufA, bufB, Wf, bias, 0, col0, l15, quad);  // L2
    __syncthreads();
    if (wm == 0) level4<1,  8>(bufB, bufA, Wf, bias, 0, col0, l15, quad);  // L3
    __syncthreads();
    if (wm == 0) level4<1,  4>(bufA, bufC, Wf, bias, 0, col0, l15, quad);  // L4
    __syncthreads();

    // ---- s1 gather ----
    gather_leafhalf(tokB, embedding, bufA, row, seg);
    __syncthreads();

    // ---- s1 levels: L0..L4, stash L4-out in bufC rows 2-3 ----
    level4<2, 64>(bufA, bufB, Wf, bias, wm * 2, col0, l15, quad);   // L0
    __syncthreads();
    level4<1, 32>(bufB, bufA, Wf, bias, wm,     col0, l15, quad);   // L1
    __syncthreads();
    if (wm == 0) level4<1, 16>(bufA, bufB, Wf, bias, 0, col0, l15, quad);  // L2
    __syncthreads();
    if (wm == 0) level4<1,  8>(bufB, bufA, Wf, bias, 0, col0, l15, quad);  // L3
    __syncthreads();
    if (wm == 0) level4<1,  4>(bufA, bufC + 2 * STRIDE, Wf, bias, 0, col0, l15, quad); // L4
    __syncthreads();

    // ---- batched L5 (wm0): bufC rows 0-3 -> bufA rows 0-1 ----
    if (wm == 0) {
      const int rclamp = l15 < 4 ? l15 : 3;          // bufC bounds; rows>=4 discarded
      floatx4 acc[4];
      mfma_k256_n4(bufC + rclamp * STRIDE + quad * 8, Wf, bias, acc);
      const int mrow = quad * 4;
#pragma unroll
      for (int i = 0; i < 4; ++i) {
        const int col = col0 + i * 16 + l15;
#pragma unroll
        for (int r = 0; r < 4; ++r) {
          const int mr = mrow + r;                   // mr<4 valid: sample mr>>1, node mr&1
          if (mr < 4) {
            float v = fast_tanh(acc[i][r]);
            bufA[(mr >> 1) * STRIDE + (mr & 1) * 128 + col] = (_Float16)v;
          }
        }
      }
    }
    __syncthreads();

    // ---- batched L6 + classifier partials (wm0) ----
    if (wm == 0) {
      // classifier weights reloaded per pair (keeps them out of the permanent set)
      float wc[4][3];
#pragma unroll
      for (int i = 0; i < 4; ++i)
#pragma unroll
        for (int o = 0; o < 3; ++o) wc[i][o] = W_cls[o * 128 + col0 + i * 16 + l15];

      floatx4 acc[4];
      mfma_k256_n4(bufA + l15 * STRIDE + quad * 8, Wf, bias, acc); // rows 0-1 = roots
      float part[2][3] = {{0.f, 0.f, 0.f}, {0.f, 0.f, 0.f}};
      if (quad == 0) {
#pragma unroll
        for (int i = 0; i < 4; ++i)
#pragma unroll
          for (int rr = 0; rr < 2; ++rr) {           // rr = sample
            float v = fast_tanh(acc[i][rr]);
#pragma unroll
            for (int o = 0; o < 3; ++o) part[rr][o] = fmaf(v, wc[i][o], part[rr][o]);
          }
      }
#pragma unroll
      for (int rr = 0; rr < 2; ++rr)
#pragma unroll
        for (int o = 0; o < 3; ++o) {
          float v = part[rr][o];                     // nonzero only in quad-0 lanes
          v += __shfl_down(v, 8);
          v += __shfl_down(v, 4);
          v += __shfl_down(v, 2);
          v += __shfl_down(v, 1);
          if (lane == 0) wavepart[wn][rr][o] = v;
        }
    }
    __syncthreads();
    if (tid < 6) {
      const int rr = tid / 3, o = tid - 3 * rr;
      out[(2 * p + rr) * 3 + o] = wavepart[0][rr][o] + wavepart[1][rr][o] + b_cls[o];
    }
    tokA = tokAn; tokB = tokBn;
    // next pair's gather overwrites bufA: all L6 bufA reads completed before the wavepart
    // barrier; wavepart next written 14 barriers later -> safe.
  }
}

extern "C" void kernel_launch(void* const* d_in, const int* in_sizes, int n_in,
                              void* d_out, int out_size, void* d_ws, size_t ws_size,
                              hipStream_t stream) {
  const int*   tokens    = (const int*)d_in[0];
  const float* embedding = (const float*)d_in[1];
  const float* W_tree    = (const float*)d_in[2];
  const float* b_tree    = (const float*)d_in[3];
  const float* W_cls     = (const float*)d_in[4];
  const float* b_cls     = (const float*)d_in[5];
  float* out = (float*)d_out;

  dim3 grid(768), block(256);   // 3 blocks/CU x 256 CUs; grid-stride over 2048 pairs
  tree_kernel<<<grid, block, 0, stream>>>(tokens, embedding, W_tree, b_tree, W_cls, b_cls, out);
}

// Round 6
// 180.437 us; speedup vs baseline: 2.9870x; 2.9870x over previous
//
#include <hip/hip_runtime.h>
#include <hip/hip_fp16.h>

// Tree NN: reps = emb[tokens] (4096 x 128 x 128); 7x: reps = tanh(concat(pairs) @ W_tree^T + b);
// out = root @ W_cls^T + b_cls.
//
// R19 = R18's 2x2 wave tiling (correctness-verified in R18: passed, absmax 0.0039) with
// the spill eliminated via REGISTER HEADROOM: lb(256,3) -> lb(256,2).
//
// R18 evidence: under the 170-reg cap, peak demand (~185: Wf 128 + acc 16 + gather 32 +
// addr) forced the allocator to spill the whole Wf[4][8] weight array -> every MFMA
// reloaded B-fragments from scratch: FETCH 1.04 GB (vs 123 MB real), WRITE 144 MB,
// VGPR_Count 84, 465 us. Rule (seen R15+R18): exceed the cap and hipcc spills the big
// loop-invariant array. lb(256,2) caps at 256: demand ~190 fits with ~60 slack -> no
// spill possible. Cost: 2 blocks/CU (8 waves, 2/SIMD, Occupancy ~25%).
//
// Payload under test (unchanged): each A-row read by 2 waves not 4 -> 320 ds_read_b128
// per pair (half of R13's 640), same MFMA count. At R13's wall no CU pipe exceeded ~50%,
// so 2-block overlap may suffice; this round is the decisive A/B for the LDS-traffic
// theory. Pre-committed read: <=75us = theory right; 85-95 = occupancy cancels gain;
// >100 = occupancy dominates -> revert to R13 core.
//
//  1. 2x2 WAVE TILING (m x n): wave (wm=wid>>1, wn=wid&1); wn owns 4 n-tiles = 64 cols
//     (Wf[4][8] = 128 VGPR), wm owns half the m-tiles at L0/L1.
//  2. Tail levels (L2..L6, single m-tile) on wm0 waves only; wm1 idles to the barrier.
//  3. grid 512 = 2 blocks/CU x 256 CUs; 2048 pairs / 512 = exactly 4 pairs per block.
// Kept: bias folded into acc init, pair-contig LDS layout, conflict-free gather writes,
// fp16 MFMA 16x16x32, fp32 accumulate/tanh, batched L5/L6 tail, plain __syncthreads.

typedef _Float16 half8 __attribute__((ext_vector_type(8)));
typedef float floatx4 __attribute__((ext_vector_type(4)));

#define STRIDE 264   // 256 + 8 fp16 pad: A-row ds_read_b128 conflict-free
#define UROW   33    // uint4 per row
#define NPAIR  2048

__device__ __forceinline__ float fast_tanh(float x) {
  // No clamp needed: e=inf -> 1; e=0 -> -1. Inputs never NaN.
  float e = __expf(2.f * x);
  return 1.f - 2.f * __builtin_amdgcn_rcpf(e + 1.f);
}

__device__ __forceinline__ unsigned pkrtz(float a, float b) {
  auto h = __builtin_amdgcn_cvt_pkrtz(a, b);   // __fp16 ext_vector(2)
  return __builtin_bit_cast(unsigned, h);
}

// Gather: thread (row=t&63, seg=t>>6) covers leaf 2*row+(seg>>1), feature-half seg&1.
// Writes 8 uint4 at row*33 + seg*8 + j: 8 consecutive lanes hit 8 consecutive rows ->
// distinct bank-quads -> conflict-free phases. Pair-contiguous layout.
__device__ __forceinline__ void gather_leafhalf(int tok, const float* __restrict__ emb,
                                                _Float16* buf, int row, int seg) {
  const float4* src = (const float4*)emb + (size_t)tok * 32 + (seg & 1) * 16;
  uint4* dst = (uint4*)buf + row * UROW + seg * 8;
#pragma unroll
  for (int j = 0; j < 8; ++j) {
    float4 x = src[2 * j], y = src[2 * j + 1];
    uint4 w;
    w.x = pkrtz(x.x, x.y); w.y = pkrtz(x.z, x.w);
    w.z = pkrtz(y.x, y.y); w.w = pkrtz(y.z, y.w);
    dst[j] = w;
  }
}

// K=256 MFMA for one 16-row m-tile, FOUR n-tiles: 4 independent 8-deep chains (ILP
// across n). One ds_read_b128 feeds 4 MFMAs. Bias in chain init.
// A-frag: A[m=lane&15][k=quad*8+j]; B-frag: B[k=quad*8+j][n=lane&15];
// D: col=lane&15, row=quad*4+reg (verified layouts, learn_hip m89/m91).
__device__ __forceinline__ void mfma_k256_n4(const _Float16* arow, const half8 (&Wf)[4][8],
                                             const float (&bias)[4], floatx4 (&acc)[4]) {
#pragma unroll
  for (int i = 0; i < 4; ++i) acc[i] = (floatx4){bias[i], bias[i], bias[i], bias[i]};
#pragma unroll
  for (int ks = 0; ks < 8; ++ks) {
    half8 x = *(const half8*)(arow + ks * 32);
#pragma unroll
    for (int i = 0; i < 4; ++i)
      acc[i] = __builtin_amdgcn_mfma_f32_16x16x32_f16(x, Wf[i][ks], acc[i], 0, 0, 0);
  }
}

// One wave: 4 n-tiles (cols [col0, col0+64)) for MT_LOC m-tiles starting at mbase.
// Sequential m (unroll 1) caps live acc at 16 VGPR. Pair-contiguous store, MOUT mask.
// Stale rows above MOUT always hold finite tanh/leaf values; masked at store.
template<int MT_LOC, int MOUT>
__device__ __forceinline__ void level4(const _Float16* inb, _Float16* outb,
                                       const half8 (&Wf)[4][8], const float (&bias)[4],
                                       int mbase, int col0, int l15, int quad)
{
#pragma unroll 1
  for (int m = 0; m < MT_LOC; ++m) {
    floatx4 acc[4];
    mfma_k256_n4(inb + ((mbase + m) * 16 + l15) * STRIDE + quad * 8, Wf, bias, acc);
    const int mrow = (mbase + m) * 16 + quad * 4;
#pragma unroll
    for (int i = 0; i < 4; ++i) {
      const int col = col0 + i * 16 + l15;
#pragma unroll
      for (int r = 0; r < 4; ++r) {
        const int node = mrow + r;
        if (MOUT == 64 || node < MOUT) {   // compile-time short-circuit for L0
          float v = fast_tanh(acc[i][r]);
          outb[(node >> 1) * STRIDE + (node & 1) * 128 + col] = (_Float16)v;
        }
      }
    }
  }
}

__global__ __launch_bounds__(256, 2)   // cap 256 VGPR: Wf[4][8]=128 + peaks ~190 fit, NO spill
void tree_kernel(const int* __restrict__ tokens,
                 const float* __restrict__ embedding,
                 const float* __restrict__ W_tree,
                 const float* __restrict__ b_tree,
                 const float* __restrict__ W_cls,
                 const float* __restrict__ b_cls,
                 float* __restrict__ out)
{
  __shared__ __align__(16) _Float16 bufA[64 * STRIDE];   // leaves / even outputs (33.8 KB)
  __shared__ __align__(16) _Float16 bufB[32 * STRIDE];   // odd outputs (16.9 KB)
  __shared__ __align__(16) _Float16 bufC[4 * STRIDE];    // pair stash: L4 outs (2.1 KB)
  __shared__ float wavepart[2][2][3];                    // classifier partials (48 B)

  const int tid  = threadIdx.x;
  const int wid  = tid >> 6;
  const int lane = tid & 63;
  const int l15  = lane & 15;
  const int quad = lane >> 4;
  const int wn   = wid & 1;                // n-half: cols [64*wn, 64*wn+64)
  const int wm   = wid >> 1;               // m-half for L0/L1; wm0 runs the tail
  const int col0 = wn * 64;
  const int row  = tid & 63;               // gather destination row
  const int seg  = tid >> 6;               // gather leaf-half / feature-half segment
  const int tidx = 2 * row + (seg >> 1);   // this thread's token index within a sample

  // ---- stage this wave's 4 n-tiles of W_tree as B-fragments (128 VGPR) ----
  // B[k][n] = W_tree[e=n][h=k]  (einsum 'bnh,eh->bne' => out = comb @ W^T)
  half8 Wf[4][8];
#pragma unroll
  for (int i = 0; i < 4; ++i) {
    const int e = col0 + i * 16 + l15;
#pragma unroll
    for (int ks = 0; ks < 8; ++ks) {
      const int k = ks * 32 + quad * 8;
      const float4* p = (const float4*)(W_tree + e * 256 + k);
      float4 lo = p[0], hi = p[1];
      half8 f;
      f[0] = (_Float16)lo.x; f[1] = (_Float16)lo.y; f[2] = (_Float16)lo.z; f[3] = (_Float16)lo.w;
      f[4] = (_Float16)hi.x; f[5] = (_Float16)hi.y; f[6] = (_Float16)hi.z; f[7] = (_Float16)hi.w;
      Wf[i][ks] = f;
    }
  }
  float bias[4];
#pragma unroll
  for (int i = 0; i < 4; ++i) bias[i] = b_tree[col0 + i * 16 + l15];

  int tokA = tokens[(2 * blockIdx.x) * 128 + tidx];       // preloaded pair tokens
  int tokB = tokens[(2 * blockIdx.x + 1) * 128 + tidx];

#pragma unroll 1
  for (int p = blockIdx.x; p < NPAIR; p += gridDim.x) {
    int pn = p + gridDim.x;
    if (pn >= NPAIR) pn = p;               // last iteration: harmless self-reload

    // ---- s0 gather (token preloaded) + preload next-pair tokens ----
    gather_leafhalf(tokA, embedding, bufA, row, seg);
    const int tokAn = tokens[(2 * pn) * 128 + tidx];
    const int tokBn = tokens[(2 * pn + 1) * 128 + tidx];
    __syncthreads();

    // ---- s0 levels: L0..L4, stash L4-out in bufC rows 0-1 ----
    level4<2, 64>(bufA, bufB, Wf, bias, wm * 2, col0, l15, quad);   // L0: wm-split
    __syncthreads();
    level4<1, 32>(bufB, bufA, Wf, bias, wm,     col0, l15, quad);   // L1: wm-split
    __syncthreads();
    if (wm == 0) level4<1, 16>(bufA, bufB, Wf, bias, 0, col0, l15, quad);  // L2
    __syncthreads();
    if (wm == 0) level4<1,  8>(bufB, bufA, Wf, bias, 0, col0, l15, quad);  // L3
    __syncthreads();
    if (wm == 0) level4<1,  4>(bufA, bufC, Wf, bias, 0, col0, l15, quad);  // L4
    __syncthreads();

    // ---- s1 gather ----
    gather_leafhalf(tokB, embedding, bufA, row, seg);
    __syncthreads();

    // ---- s1 levels: L0..L4, stash L4-out in bufC rows 2-3 ----
    level4<2, 64>(bufA, bufB, Wf, bias, wm * 2, col0, l15, quad);   // L0
    __syncthreads();
    level4<1, 32>(bufB, bufA, Wf, bias, wm,     col0, l15, quad);   // L1
    __syncthreads();
    if (wm == 0) level4<1, 16>(bufA, bufB, Wf, bias, 0, col0, l15, quad);  // L2
    __syncthreads();
    if (wm == 0) level4<1,  8>(bufB, bufA, Wf, bias, 0, col0, l15, quad);  // L3
    __syncthreads();
    if (wm == 0) level4<1,  4>(bufA, bufC + 2 * STRIDE, Wf, bias, 0, col0, l15, quad); // L4
    __syncthreads();

    // ---- batched L5 (wm0): bufC rows 0-3 -> bufA rows 0-1 ----
    if (wm == 0) {
      const int rclamp = l15 < 4 ? l15 : 3;          // bufC bounds; rows>=4 discarded
      floatx4 acc[4];
      mfma_k256_n4(bufC + rclamp * STRIDE + quad * 8, Wf, bias, acc);
      const int mrow = quad * 4;
#pragma unroll
      for (int i = 0; i < 4; ++i) {
        const int col = col0 + i * 16 + l15;
#pragma unroll
        for (int r = 0; r < 4; ++r) {
          const int mr = mrow + r;                   // mr<4 valid: sample mr>>1, node mr&1
          if (mr < 4) {
            float v = fast_tanh(acc[i][r]);
            bufA[(mr >> 1) * STRIDE + (mr & 1) * 128 + col] = (_Float16)v;
          }
        }
      }
    }
    __syncthreads();

    // ---- batched L6 + classifier partials (wm0) ----
    if (wm == 0) {
      // classifier weights reloaded per pair (keeps them out of the permanent set)
      float wc[4][3];
#pragma unroll
      for (int i = 0; i < 4; ++i)
#pragma unroll
        for (int o = 0; o < 3; ++o) wc[i][o] = W_cls[o * 128 + col0 + i * 16 + l15];

      floatx4 acc[4];
      mfma_k256_n4(bufA + l15 * STRIDE + quad * 8, Wf, bias, acc); // rows 0-1 = roots
      float part[2][3] = {{0.f, 0.f, 0.f}, {0.f, 0.f, 0.f}};
      if (quad == 0) {
#pragma unroll
        for (int i = 0; i < 4; ++i)
#pragma unroll
          for (int rr = 0; rr < 2; ++rr) {           // rr = sample
            float v = fast_tanh(acc[i][rr]);
#pragma unroll
            for (int o = 0; o < 3; ++o) part[rr][o] = fmaf(v, wc[i][o], part[rr][o]);
          }
      }
#pragma unroll
      for (int rr = 0; rr < 2; ++rr)
#pragma unroll
        for (int o = 0; o < 3; ++o) {
          float v = part[rr][o];                     // nonzero only in quad-0 lanes
          v += __shfl_down(v, 8);
          v += __shfl_down(v, 4);
          v += __shfl_down(v, 2);
          v += __shfl_down(v, 1);
          if (lane == 0) wavepart[wn][rr][o] = v;
        }
    }
    __syncthreads();
    if (tid < 6) {
      const int rr = tid / 3, o = tid - 3 * rr;
      out[(2 * p + rr) * 3 + o] = wavepart[0][rr][o] + wavepart[1][rr][o] + b_cls[o];
    }
    tokA = tokAn; tokB = tokBn;
    // next pair's gather overwrites bufA: all L6 bufA reads completed before the wavepart
    // barrier; wavepart next written 14 barriers later -> safe.
  }
}

extern "C" void kernel_launch(void* const* d_in, const int* in_sizes, int n_in,
                              void* d_out, int out_size, void* d_ws, size_t ws_size,
                              hipStream_t stream) {
  const int*   tokens    = (const int*)d_in[0];
  const float* embedding = (const float*)d_in[1];
  const float* W_tree    = (const float*)d_in[2];
  const float* b_tree    = (const float*)d_in[3];
  const float* W_cls     = (const float*)d_in[4];
  const float* b_cls     = (const float*)d_in[5];
  float* out = (float*)d_out;

  dim3 grid(512), block(256);   // 2 blocks/CU x 256 CUs; 4 pairs per block exactly
  tree_kernel<<<grid, block, 0, stream>>>(tokens, embedding, W_tree, b_tree, W_cls, b_cls, out);
}